// Round 2
// baseline (206.857 us; speedup 1.0000x reference)
//
#include <hip/hip_runtime.h>

// CTC forward loss, B=256, T=1024, C=128, L=64, S=2L+1=129, BLANK=127.
// One wave per batch element (256 blocks x 64 threads). Latency-chain bound:
// occupancy tricks cannot help (wall time = one wave's serial 1023-step DP);
// only chain shortening / stall removal can.
//
// Round 10 (vs verified 210.6us R8): R8 still did 2 ds_read per DP step
// (4-deep ring). 210.6us = ~257 cyc/step @1.25GHz == the same floor as the
// R2-R7 global-gather versions -> hypothesis: the per-step LDS round trip
// (solo-wave ds_read latency ~120cyc, m117) is on the critical path exactly
// like the global gather was. This round removes ALL memory ops from the
// compute body:
//   - register operand block: 32 rows x {lab,blank} = 64 VGPRs per buffer,
//     double-buffered (regA/regB, outer loop unrolled x2 so every array
//     index is compile-time -> stays in registers),
//   - LDS is a 3-deep rotating stage (3 x 16KB): during chunk c's pure-VALU
//     compute we stage chunk c+2 (global_load_lds w16) and burst-read chunk
//     c+1 (64 ds_read_b32) into the other register buffer,
//   - ONE vmcnt(0) per 32 steps; lgkm waits compiler-placed at first use.
// DP math (LSTEP/RENORM4, linear domain + per-lane exponent, absmax 0.0 in
// rounds 6/7) is byte-identical.

#define B_     256
#define T_     1024
#define C_     128
#define L_     64
#define BLANK_ 127
#define EPS_   1e-7f
#define LN2_   0.69314718055994530942f
#define ROWS   32
#define LDSF   (ROWS * C_)      // 4096 floats = 16 KB per buffer

__device__ __forceinline__ float flog2(float x) { return __builtin_amdgcn_logf(x); }

template <int CTRL>
__device__ __forceinline__ int dpp_i(int x) {
    return __builtin_amdgcn_update_dpp(x, x, CTRL, 0xF, 0xF, false);
}
// whole-wave rotate: lane i receives lane (i-1)&63
__device__ __forceinline__ float ror1_f(float x) {
    return __int_as_float(dpp_i<0x13C>(__float_as_int(x)));
}
__device__ __forceinline__ int ror1_i(int x) { return dpp_i<0x13C>(x); }

__device__ __forceinline__ float fldexp(float x, int n) {
#if __has_builtin(__builtin_amdgcn_ldexpf)
    return __builtin_amdgcn_ldexpf(x, n);
#else
    return ldexpf(x, n);
#endif
}
// frexp-style exponent; 0 for x==0
__device__ __forceinline__ int fexp_of(float x) {
#if __has_builtin(__builtin_amdgcn_frexp_expf)
    return __builtin_amdgcn_frexp_expf(x);
#else
    const int bx = (__float_as_int(x) >> 23) & 0xFF;
    return (x > 0.0f) ? (bx - 126) : 0;
#endif
}

// global -> LDS direct copy, 16 B/lane (1 KB/instr). LDS dest is the
// wave-uniform base; HW lands lane i at base + i*16.
typedef const __attribute__((address_space(1))) void gas_void;
typedef __attribute__((address_space(3))) void las_void;
__device__ __forceinline__ void g2l16(const float* g, float* l) {
    __builtin_amdgcn_global_load_lds((gas_void*)g, (las_void*)l, 16, 0, 0);
}
__device__ __forceinline__ void g2l4(const float* g, float* l) {
    __builtin_amdgcn_global_load_lds((gas_void*)g, (las_void*)l, 4, 0, 0);
}

// One DP step (verified math from rounds 6/7): linear recursion on f32
// mantissas with per-lane int exponent e; dead lanes adopt the neighbor's
// exponent so the DP front is never flushed; ldexp(0,n)=0 keeps lane-0
// wraparound garbage out of live arithmetic (prevE cndmask'd, sk gated).
#define LSTEP(pL, pB)                                                         \
    {                                                                         \
        const float pBe = (pB) + EPS_;                                        \
        const float pLe = (pL) + EPS_;                                        \
        const int   ep  = ror1_i(e);                                          \
        const float mpE = ror1_f(aE);                                         \
        const float mpO = ror1_f(aO);                                         \
        const bool dead = (fmaxf(aE, aO) == 0.0f);                            \
        e = dead ? ep : e;                                                    \
        const int   d   = ep - e;                                             \
        float prevE = fldexp(mpE, d);                                         \
        const float prevO = fldexp(mpO, d);                                   \
        prevE = isL0 ? fldexp(a0, e0 - e) : prevE;                            \
        const float sk = can_skip ? prevO : 0.0f;                             \
        const float nE = (aE + aO) * pBe;                                     \
        const float nO = (aO + prevE + sk) * pLe;                             \
        a0 *= pBe;                                                            \
        aE = nE; aO = nO;                                                     \
    }

// Renorm every 4 steps (shrink >= pmin^4 = 2^-68: no underflow; growth <=
// 6^4: no overflow). frexp_exp(0)=0 so dead lanes are a no-op.
#define RENORM4                                                               \
    {                                                                         \
        const int x = fexp_of(fmaxf(aE, aO));                                 \
        aE = fldexp(aE, -x); aO = fldexp(aO, -x); e += x;                     \
        const int x0 = fexp_of(a0);                                           \
        a0 = fldexp(a0, -x0); e0 += x0;                                       \
    }

// Stage chunk k (rows t = 1+32k .. 32+32k; k==31 -> final 31 rows) into
// LDS at float offset LOFF. k may be a runtime int; branch is wave-uniform.
#define STAGE_CHUNK(k, LOFF)                                                  \
    {                                                                         \
        const float* src = base + (size_t)(1 + 32 * (k)) * C_;                \
        const int nKB = ((k) == 31) ? 15 : 16;                                \
        for (int j = 0; j < nKB; ++j)                                         \
            g2l16(src + j * 256 + lane * 4, sm + (LOFF) + j * 256);           \
        if ((k) == 31) {                                                      \
            const float* s2 = src + 15 * 256;                                 \
            g2l4(s2 + lane,      sm + (LOFF) + 15 * 256);                     \
            g2l4(s2 + 64 + lane, sm + (LOFF) + 15 * 256 + 64);                \
        }                                                                     \
    }

// Burst-read NR rows' {lab, blank} operands from LDS at LOFF into register
// arrays RL/RB. All indices compile-time (full unroll) -> registers.
#define BURST(LOFF, RL, RB, NR)                                               \
    {                                                                         \
        _Pragma("unroll")                                                     \
        for (int j = 0; j < (NR); ++j) {                                      \
            RL[j] = sm[(LOFF) + j * C_ + lab];                                \
            RB[j] = sm[(LOFF) + j * C_ + BLANK_];                             \
        }                                                                     \
    }

// NS pure-VALU DP steps from register operands.
#define CHUNK_COMPUTE(RL, RB, NS)                                             \
    {                                                                         \
        _Pragma("unroll")                                                     \
        for (int k = 0; k < (NS); ++k) {                                      \
            LSTEP(RL[k], RB[k])                                               \
            if ((k & 3) == 3) RENORM4                                         \
        }                                                                     \
    }

#define VMWAIT asm volatile("s_waitcnt vmcnt(0)" ::: "memory")

__global__ __launch_bounds__(64, 1)
void ctc_fwd(const int* __restrict__ yt, const float* __restrict__ yp,
             float* __restrict__ out) {
    __shared__ float sm[3 * LDSF];                // 48 KB, 3-deep rotation

    const int b    = blockIdx.x;
    const int lane = threadIdx.x;                 // 0..63
    const int lab  = yt[b * L_ + lane];           // label of state 2*lane+1
    const int labp = __shfl_up(lab, 1);           // init-only, off hot path
    const bool can_skip = (lane > 0) && (lab != labp);
    const bool isL0     = (lane == 0);

    const float* __restrict__ base = yp + (size_t)b * T_ * C_;

    // ---- prologue: stage chunks 0 and 1 (rows 1..64) ----
    STAGE_CHUNK(0, 0)
    STAGE_CHUNK(1, LDSF)

    // ---- t=0 init (linear, exponent 0): only states 0 and 1 reachable ----
    float a0 = base[BLANK_] + EPS_;               // state 0 (uniform)
    float aO = isL0 ? (base[lab] + EPS_) : 0.0f;  // state 2i+1
    float aE = 0.0f;                              // state 2i+2
    int   e  = 0, e0 = 0;

    VMWAIT;                                       // chunks 0,1 + init loads

    // ---- register operand double-buffer ----
    float rLA[32], rBA[32], rLB[32], rBB[32];
    BURST(0, rLA, rBA, 32)                        // chunk 0 -> regA

    // ---- 15 chunk-pairs: chunks 0..29 (t = 1..960) ----
#pragma unroll 1
    for (int c = 0; c < 30; c += 2) {
        {   // even half: compute chunk c from regA; stage c+2; burst c+1->regB
            const int lo_s = ((c + 2) % 3) * LDSF;
            const int lo_b = ((c + 1) % 3) * LDSF;
            STAGE_CHUNK(c + 2, lo_s)
            BURST(lo_b, rLB, rBB, 32)
            CHUNK_COMPUTE(rLA, rBA, 32)
            VMWAIT;                               // stage c+2 landed
        }
        {   // odd half: compute chunk c+1 from regB; stage c+3; burst c+2->regA
            const int lo_s = ((c + 3) % 3) * LDSF;
            const int lo_b = ((c + 2) % 3) * LDSF;
            STAGE_CHUNK(c + 3, lo_s)              // c=28 stages chunk 31 (31 rows)
            BURST(lo_b, rLA, rBA, 32)
            CHUNK_COMPUTE(rLB, rBB, 32)
            VMWAIT;                               // stage c+3 landed
        }
    }

    // ---- chunk 30 (t = 961..992) from regA; burst chunk 31 -> regB ----
    {
        const int lo_b = (31 % 3) * LDSF;         // chunk 31 staged at c=28 odd half
        BURST(lo_b, rLB, rBB, 31)
        CHUNK_COMPUTE(rLA, rBA, 32)
    }

    // ---- final chunk 31: t = 993..1023 (31 steps) from regB ----
    CHUNK_COMPUTE(rLB, rBB, 31)

    // loss = -ln(alpha[127] + alpha[128]); both live in lane 63 at scale 2^e.
    if (lane == 63) {
        const float s = aE + aO;                  // in [2^-70, 8): v_log safe
        out[b] = -(flog2(s) + (float)e) * LN2_;
    }
}

extern "C" void kernel_launch(void* const* d_in, const int* in_sizes, int n_in,
                              void* d_out, int out_size, void* d_ws, size_t ws_size,
                              hipStream_t stream) {
    const int*   y_true = (const int*)d_in[0];
    const float* y_pred = (const float*)d_in[1];
    float*       out    = (float*)d_out;
    ctc_fwd<<<B_, 64, 0, stream>>>(y_true, y_pred, out);
}

// Round 3
// 196.738 us; speedup vs baseline: 1.0514x; 1.0514x over previous
//
#include <hip/hip_runtime.h>

// CTC forward loss, B=256, T=1024, C=128, L=64, S=2L+1=129, BLANK=127.
// One wave per batch element (256 blocks x 64 threads). Serial-chain bound:
// R8 (2 ds_read/step) == R10 (zero memory ops in compute body) == ~207us,
// so the per-step memory hypothesis is dead; the floor is the LSTEP
// dependent chain itself.
//
// Round 11: remove the per-lane exponent machinery from the hot path.
//   - constant prescale: every step multiplies by (p+EPS)*2^7 via one fma
//     (bit-identical mantissa to (p+EPS), exact pow2 scale),
//   - wave-UNIFORM renorm every 16 steps: DPP max-reduce -> readlane 63 ->
//     frexp -> uniform ldexp on {aE,aO,a0}; e (uniform) += x. Off the
//     per-step chain; compiler schedules the independent reduce ops into
//     LSTEP stall slots.
//   - LSTEP chain: ror1 -> cndmask -> add -> add -> mul (5 deps; was 8 + no
//     ror1_i/fldexp/dead-adoption). All adds see operands at identical
//     relative scale 2^(7k), so mantissa arithmetic is bit-identical to the
//     per-lane-exponent scheme; only lanes >~100 bits below wave max flush
//     to 0 (sub-ulp contributions to the final logaddexp).
//   - final: true = stored * 2^(e - 7*1023); out = -(log2(s)+e-7161)*ln2.
// Memory path (3-deep LDS rotation + register operand double-buffer, one
// vmcnt(0)/32 steps) unchanged from R10.

#define B_     256
#define T_     1024
#define C_     128
#define L_     64
#define BLANK_ 127
#define EPS_   1e-7f
#define LN2_   0.69314718055994530942f
#define ROWS   32
#define LDSF   (ROWS * C_)      // 4096 floats = 16 KB per buffer
#define PRE_   128.0f           // 2^7 per-step prescale
#define EPSP_  (EPS_ * PRE_)    // fma(p, 2^7, EPS*2^7) == (p+EPS)*2^7 exactly

__device__ __forceinline__ float flog2(float x) { return __builtin_amdgcn_logf(x); }

template <int CTRL>
__device__ __forceinline__ int dpp_i(int x) {
    return __builtin_amdgcn_update_dpp(x, x, CTRL, 0xF, 0xF, false);
}
// whole-wave rotate: lane i receives lane (i-1)&63
__device__ __forceinline__ float ror1_f(float x) {
    return __int_as_float(dpp_i<0x13C>(__float_as_int(x)));
}
// one level of the 64-lane max reduction
template <int CTRL>
__device__ __forceinline__ float maxlvl(float m) {
    return fmaxf(m, __int_as_float(dpp_i<CTRL>(__float_as_int(m))));
}

__device__ __forceinline__ float fldexp(float x, int n) {
#if __has_builtin(__builtin_amdgcn_ldexpf)
    return __builtin_amdgcn_ldexpf(x, n);
#else
    return ldexpf(x, n);
#endif
}
// frexp-style exponent; 0 for x==0
__device__ __forceinline__ int fexp_of(float x) {
#if __has_builtin(__builtin_amdgcn_frexp_expf)
    return __builtin_amdgcn_frexp_expf(x);
#else
    const int bx = (__float_as_int(x) >> 23) & 0xFF;
    return (x > 0.0f) ? (bx - 126) : 0;
#endif
}

// global -> LDS direct copy, 16 B/lane (1 KB/instr). LDS dest is the
// wave-uniform base; HW lands lane i at base + i*16.
typedef const __attribute__((address_space(1))) void gas_void;
typedef __attribute__((address_space(3))) void las_void;
__device__ __forceinline__ void g2l16(const float* g, float* l) {
    __builtin_amdgcn_global_load_lds((gas_void*)g, (las_void*)l, 16, 0, 0);
}
__device__ __forceinline__ void g2l4(const float* g, float* l) {
    __builtin_amdgcn_global_load_lds((gas_void*)g, (las_void*)l, 4, 0, 0);
}

// One DP step, uniform-exponent scheme. Chain: ror1 -> cndmask -> add ->
// add -> mul. Lane-0 wraparound garbage is cndmask'd (prevE <- a0) or gated
// (can_skip=false on lane 0). Dead (not-yet-reached) lanes hold exact 0.
#define LSTEP(pL, pB)                                                         \
    {                                                                         \
        const float pBe = __builtin_fmaf((pB), PRE_, EPSP_);                  \
        const float pLe = __builtin_fmaf((pL), PRE_, EPSP_);                  \
        const float mpE = ror1_f(aE);                                         \
        const float mpO = ror1_f(aO);                                         \
        const float prevE = isL0 ? a0 : mpE;                                  \
        const float sk    = can_skip ? mpO : 0.0f;                            \
        const float nE = (aE + aO) * pBe;                                     \
        const float nO = (aO + prevE + sk) * pLe;                             \
        a0 *= pBe;                                                            \
        aE = nE; aO = nO;                                                     \
    }

// Wave-uniform renorm: full 64-lane max (DPP shr 1/2/4/8 + bcast15/31 ->
// lane 63), broadcast exponent, exact pow2 rescale. Runs every 16 steps;
// drift bounds: up <= ~2^(+4/step), down >= ~2^(-2/step) -> no overflow,
// max never flushes. e (wave-uniform) accumulates Sum(x).
#define RENORM16                                                              \
    {                                                                         \
        float m = fmaxf(fmaxf(aE, aO), a0);                                   \
        m = maxlvl<0x111>(m);                                                 \
        m = maxlvl<0x112>(m);                                                 \
        m = maxlvl<0x114>(m);                                                 \
        m = maxlvl<0x118>(m);                                                 \
        m = maxlvl<0x142>(m);                                                 \
        m = maxlvl<0x143>(m);                                                 \
        const int x = fexp_of(__int_as_float(                                 \
            __builtin_amdgcn_readlane(__float_as_int(m), 63)));               \
        aE = fldexp(aE, -x); aO = fldexp(aO, -x); a0 = fldexp(a0, -x);        \
        e += x;                                                               \
    }

// Stage chunk k (rows t = 1+32k .. 32+32k; k==31 -> final 31 rows) into
// LDS at float offset LOFF. k may be a runtime int; branch is wave-uniform.
#define STAGE_CHUNK(k, LOFF)                                                  \
    {                                                                         \
        const float* src = base + (size_t)(1 + 32 * (k)) * C_;                \
        const int nKB = ((k) == 31) ? 15 : 16;                                \
        for (int j = 0; j < nKB; ++j)                                         \
            g2l16(src + j * 256 + lane * 4, sm + (LOFF) + j * 256);           \
        if ((k) == 31) {                                                      \
            const float* s2 = src + 15 * 256;                                 \
            g2l4(s2 + lane,      sm + (LOFF) + 15 * 256);                     \
            g2l4(s2 + 64 + lane, sm + (LOFF) + 15 * 256 + 64);                \
        }                                                                     \
    }

// Burst-read NR rows' {lab, blank} operands from LDS at LOFF into register
// arrays RL/RB. All indices compile-time (full unroll) -> registers.
#define BURST(LOFF, RL, RB, NR)                                               \
    {                                                                         \
        _Pragma("unroll")                                                     \
        for (int j = 0; j < (NR); ++j) {                                      \
            RL[j] = sm[(LOFF) + j * C_ + lab];                                \
            RB[j] = sm[(LOFF) + j * C_ + BLANK_];                             \
        }                                                                     \
    }

// NS pure-VALU DP steps from register operands; uniform renorm at k=15,31.
#define CHUNK_COMPUTE(RL, RB, NS)                                             \
    {                                                                         \
        _Pragma("unroll")                                                     \
        for (int k = 0; k < (NS); ++k) {                                      \
            LSTEP(RL[k], RB[k])                                               \
            if ((k & 15) == 15) RENORM16                                      \
        }                                                                     \
    }

#define VMWAIT asm volatile("s_waitcnt vmcnt(0)" ::: "memory")

__global__ __launch_bounds__(64, 1)
void ctc_fwd(const int* __restrict__ yt, const float* __restrict__ yp,
             float* __restrict__ out) {
    __shared__ float sm[3 * LDSF];                // 48 KB, 3-deep rotation

    const int b    = blockIdx.x;
    const int lane = threadIdx.x;                 // 0..63
    const int lab  = yt[b * L_ + lane];           // label of state 2*lane+1
    const int labp = __shfl_up(lab, 1);           // init-only, off hot path
    const bool can_skip = (lane > 0) && (lab != labp);
    const bool isL0     = (lane == 0);

    const float* __restrict__ base = yp + (size_t)b * T_ * C_;

    // ---- prologue: stage chunks 0 and 1 (rows 1..64) ----
    STAGE_CHUNK(0, 0)
    STAGE_CHUNK(1, LDSF)

    // ---- t=0 init (exponent 0, no prescale): states 0 and 1 reachable ----
    float a0 = base[BLANK_] + EPS_;               // state 0 (uniform)
    float aO = isL0 ? (base[lab] + EPS_) : 0.0f;  // state 2i+1
    float aE = 0.0f;                              // state 2i+2
    int   e  = 0;                                 // wave-uniform renorm accum

    VMWAIT;                                       // chunks 0,1 + init loads

    // ---- register operand double-buffer ----
    float rLA[32], rBA[32], rLB[32], rBB[32];
    BURST(0, rLA, rBA, 32)                        // chunk 0 -> regA

    // ---- 15 chunk-pairs: chunks 0..29 (t = 1..960) ----
#pragma unroll 1
    for (int c = 0; c < 30; c += 2) {
        {   // even half: compute chunk c from regA; stage c+2; burst c+1->regB
            const int lo_s = ((c + 2) % 3) * LDSF;
            const int lo_b = ((c + 1) % 3) * LDSF;
            STAGE_CHUNK(c + 2, lo_s)
            BURST(lo_b, rLB, rBB, 32)
            CHUNK_COMPUTE(rLA, rBA, 32)
            VMWAIT;                               // stage c+2 landed
        }
        {   // odd half: compute chunk c+1 from regB; stage c+3; burst c+2->regA
            const int lo_s = ((c + 3) % 3) * LDSF;
            const int lo_b = ((c + 2) % 3) * LDSF;
            STAGE_CHUNK(c + 3, lo_s)              // c=28 stages chunk 31 (31 rows)
            BURST(lo_b, rLA, rBA, 32)
            CHUNK_COMPUTE(rLB, rBB, 32)
            VMWAIT;                               // stage c+3 landed
        }
    }

    // ---- chunk 30 (t = 961..992) from regA; burst chunk 31 -> regB ----
    {
        const int lo_b = (31 % 3) * LDSF;         // chunk 31 staged at c=28 odd half
        BURST(lo_b, rLB, rBB, 31)
        CHUNK_COMPUTE(rLA, rBA, 32)
    }

    // ---- final chunk 31: t = 993..1023 (31 steps) from regB ----
    CHUNK_COMPUTE(rLB, rBB, 31)

    // loss = -ln(alpha[127] + alpha[128]); both live in lane 63.
    // true = stored * 2^(e - 7*1023)  (1023 prescaled steps, renorms e+=x).
    if (lane == 63) {
        const float s = aE + aO;
        out[b] = -(flog2(s) + (float)(e - 7161)) * LN2_;
    }
}

extern "C" void kernel_launch(void* const* d_in, const int* in_sizes, int n_in,
                              void* d_out, int out_size, void* d_ws, size_t ws_size,
                              hipStream_t stream) {
    const int*   y_true = (const int*)d_in[0];
    const float* y_pred = (const float*)d_in[1];
    float*       out    = (float*)d_out;
    ctc_fwd<<<B_, 64, 0, stream>>>(y_true, y_pred, out);
}